// Round 1
// baseline (530.258 us; speedup 1.0000x reference)
//
#include <hip/hip_runtime.h>
#include <math.h>

#define N_PIX (1024 * 1024)
#define NSEG 1024
#define NCH 32
#define NEDGE 8192
#define EPS 1e-8f
#define INV_TAU 2.0f

// ws layout (floats):
//  gsum  [32][1024]  off 0        (layout [c][s])
//  gcnt  [1024]      off 32768
//  means [1024][32]  off 33792    (layout [s][c] for float4 gather)
//  mn    [1024]      off 66560    (clamped mean norms)
//  acc   [2]         off 67584    acc0 = sum_exp (intra+inter), acc1 = sum_intra
#define OFF_GSUM 0
#define OFF_GCNT 32768
#define OFF_MEANS 33792
#define OFF_MN 66560
#define OFF_ACC 67584
#define ZERO_FLOATS (OFF_ACC + 2)

// ---------------------------------------------------------------------------
// Kernel 1: per-segment sums. 256 blocks = 32 channels x 8 pixel chunks.
// bid = j + 8*c  ->  XCD (bid%8) == chunk j, so all 32 channel-blocks of a
// chunk share one XCD's L2 for the seg reads. Each block privatizes a 4KB
// LDS histogram for its channel (bank = s%32, well spread), then flushes
// 1024 coalesced global atomics.
// ---------------------------------------------------------------------------
__global__ __launch_bounds__(1024) void k_segsum(const float* __restrict__ emb,
                                                 const int* __restrict__ seg,
                                                 float* __restrict__ gsum,
                                                 float* __restrict__ gcnt) {
    __shared__ float lsum[NSEG];
    __shared__ float lcnt[NSEG];
    const int bid = blockIdx.x;
    const int c = bid >> 3;   // channel 0..31
    const int j = bid & 7;    // pixel chunk 0..7
    const int t = threadIdx.x;

    lsum[t] = 0.0f;
    if (c == 0) lcnt[t] = 0.0f;
    __syncthreads();

    const int chunk = N_PIX / 8;  // 131072 pixels
    const int base = j * chunk;
    const float* ec = emb + (size_t)c * N_PIX + base;
    const int* sg = seg + base;

    // 1024 threads * 32 iters * 4 pixels = 131072
#pragma unroll 4
    for (int it = 0; it < chunk / (1024 * 4); ++it) {
        const int idx = (it * 1024 + t) * 4;
        const float4 v = *(const float4*)(ec + idx);
        const int4 s4 = *(const int4*)(sg + idx);
        atomicAdd(&lsum[s4.x], v.x);
        atomicAdd(&lsum[s4.y], v.y);
        atomicAdd(&lsum[s4.z], v.z);
        atomicAdd(&lsum[s4.w], v.w);
        if (c == 0) {
            atomicAdd(&lcnt[s4.x], 1.0f);
            atomicAdd(&lcnt[s4.y], 1.0f);
            atomicAdd(&lcnt[s4.z], 1.0f);
            atomicAdd(&lcnt[s4.w], 1.0f);
        }
    }
    __syncthreads();

    atomicAdd(&gsum[c * NSEG + t], lsum[t]);
    if (c == 0) atomicAdd(&gcnt[t], lcnt[t]);
}

// ---------------------------------------------------------------------------
// Kernel 2: means (layout [s][c]) + clamped norms. One thread per segment.
// gsum reads are coalesced ([c][s] layout, s = lane).
// ---------------------------------------------------------------------------
__global__ void k_means(const float* __restrict__ gsum,
                        const float* __restrict__ gcnt,
                        float* __restrict__ means, float* __restrict__ mn) {
    const int s = blockIdx.x * blockDim.x + threadIdx.x;
    if (s >= NSEG) return;
    const float cnt = fmaxf(gcnt[s], 1.0f);
    const float inv = 1.0f / cnt;
    float nrm = 0.0f;
#pragma unroll
    for (int c = 0; c < NCH; ++c) {
        const float m = gsum[c * NSEG + s] * inv;
        means[s * NCH + c] = m;
        nrm += m * m;
    }
    mn[s] = fmaxf(sqrtf(nrm), EPS);
}

// ---------------------------------------------------------------------------
// Kernel 3: per-pixel intra = cos(mean[seg], emb) * 2; accumulate
// sum(exp(intra)) and sum(intra). 4 pixels/thread, float4 loads per channel.
// ---------------------------------------------------------------------------
__global__ __launch_bounds__(1024) void k_intra(const float* __restrict__ emb,
                                                const int* __restrict__ seg,
                                                const float* __restrict__ means,
                                                const float* __restrict__ mn,
                                                float* __restrict__ acc) {
    const int g = blockIdx.x * 1024 + threadIdx.x;
    const int n0 = g * 4;
    const int4 s4 = *(const int4*)(seg + n0);

    float dot0 = 0.f, dot1 = 0.f, dot2 = 0.f, dot3 = 0.f;
    float nr0 = 0.f, nr1 = 0.f, nr2 = 0.f, nr3 = 0.f;

#pragma unroll
    for (int c0 = 0; c0 < NCH; c0 += 4) {
        const float4 e0 = *(const float4*)(emb + (size_t)(c0 + 0) * N_PIX + n0);
        const float4 e1 = *(const float4*)(emb + (size_t)(c0 + 1) * N_PIX + n0);
        const float4 e2 = *(const float4*)(emb + (size_t)(c0 + 2) * N_PIX + n0);
        const float4 e3 = *(const float4*)(emb + (size_t)(c0 + 3) * N_PIX + n0);
        const float4 m0 = *(const float4*)(means + s4.x * NCH + c0);
        const float4 m1 = *(const float4*)(means + s4.y * NCH + c0);
        const float4 m2 = *(const float4*)(means + s4.z * NCH + c0);
        const float4 m3 = *(const float4*)(means + s4.w * NCH + c0);

        dot0 += m0.x * e0.x + m0.y * e1.x + m0.z * e2.x + m0.w * e3.x;
        dot1 += m1.x * e0.y + m1.y * e1.y + m1.z * e2.y + m1.w * e3.y;
        dot2 += m2.x * e0.z + m2.y * e1.z + m2.z * e2.z + m2.w * e3.z;
        dot3 += m3.x * e0.w + m3.y * e1.w + m3.z * e2.w + m3.w * e3.w;

        nr0 += e0.x * e0.x + e1.x * e1.x + e2.x * e2.x + e3.x * e3.x;
        nr1 += e0.y * e0.y + e1.y * e1.y + e2.y * e2.y + e3.y * e3.y;
        nr2 += e0.z * e0.z + e1.z * e1.z + e2.z * e2.z + e3.z * e3.z;
        nr3 += e0.w * e0.w + e1.w * e1.w + e2.w * e2.w + e3.w * e3.w;
    }

    float esum = 0.0f, isum = 0.0f;
    {
        const float i0 = dot0 / (fmaxf(sqrtf(nr0), EPS) * mn[s4.x]) * INV_TAU;
        const float i1 = dot1 / (fmaxf(sqrtf(nr1), EPS) * mn[s4.y]) * INV_TAU;
        const float i2 = dot2 / (fmaxf(sqrtf(nr2), EPS) * mn[s4.z]) * INV_TAU;
        const float i3 = dot3 / (fmaxf(sqrtf(nr3), EPS) * mn[s4.w]) * INV_TAU;
        esum = expf(i0) + expf(i1) + expf(i2) + expf(i3);
        isum = i0 + i1 + i2 + i3;
    }

    // wave (64-lane) reduce, then per-block reduce, then 2 atomics
#pragma unroll
    for (int off = 32; off > 0; off >>= 1) {
        esum += __shfl_down(esum, off);
        isum += __shfl_down(isum, off);
    }
    __shared__ float we[16], wi[16];
    const int wid = threadIdx.x >> 6;
    const int lane = threadIdx.x & 63;
    if (lane == 0) { we[wid] = esum; wi[wid] = isum; }
    __syncthreads();
    if (threadIdx.x == 0) {
        float a = 0.f, b = 0.f;
#pragma unroll
        for (int w = 0; w < 16; ++w) { a += we[w]; b += wi[w]; }
        atomicAdd(&acc[0], a);
        atomicAdd(&acc[1], b);
    }
}

// ---------------------------------------------------------------------------
// Kernel 4: inter edges — cos(mean[a], mean[b]) * 2, accumulate exp into acc0.
// ---------------------------------------------------------------------------
__global__ void k_inter(const int* __restrict__ edges,
                        const float* __restrict__ means,
                        const float* __restrict__ mn,
                        float* __restrict__ acc) {
    const int e = blockIdx.x * 256 + threadIdx.x;
    const int a = edges[e];
    const int b = edges[NEDGE + e];
    float dot = 0.0f;
#pragma unroll
    for (int c0 = 0; c0 < NCH; c0 += 4) {
        const float4 ma = *(const float4*)(means + a * NCH + c0);
        const float4 mb = *(const float4*)(means + b * NCH + c0);
        dot += ma.x * mb.x + ma.y * mb.y + ma.z * mb.z + ma.w * mb.w;
    }
    float ex = expf(dot / (mn[a] * mn[b]) * INV_TAU);
#pragma unroll
    for (int off = 32; off > 0; off >>= 1) ex += __shfl_down(ex, off);
    __shared__ float we[4];
    const int wid = threadIdx.x >> 6;
    const int lane = threadIdx.x & 63;
    if (lane == 0) we[wid] = ex;
    __syncthreads();
    if (threadIdx.x == 0) {
        atomicAdd(&acc[0], we[0] + we[1] + we[2] + we[3]);
    }
}

// ---------------------------------------------------------------------------
// Kernel 5: out = log(sum_exp) - sum_intra / N
// ---------------------------------------------------------------------------
__global__ void k_final(const float* __restrict__ acc, float* __restrict__ out) {
    out[0] = logf(acc[0]) - acc[1] * (1.0f / (float)N_PIX);
}

extern "C" void kernel_launch(void* const* d_in, const int* in_sizes, int n_in,
                              void* d_out, int out_size, void* d_ws, size_t ws_size,
                              hipStream_t stream) {
    (void)in_sizes; (void)n_in; (void)out_size; (void)ws_size;
    const float* emb = (const float*)d_in[0];   // (32, 1024*1024) channel-major
    const int* seg = (const int*)d_in[1];       // (1024*1024,)
    const int* edges = (const int*)d_in[2];     // (2, 8192)
    float* out = (float*)d_out;

    float* ws = (float*)d_ws;
    float* gsum = ws + OFF_GSUM;
    float* gcnt = ws + OFF_GCNT;
    float* means = ws + OFF_MEANS;
    float* mn = ws + OFF_MN;
    float* acc = ws + OFF_ACC;

    // zero sums/counts/accumulators (ws is poisoned 0xAA before every launch)
    hipMemsetAsync(d_ws, 0, (size_t)ZERO_FLOATS * sizeof(float), stream);

    k_segsum<<<256, 1024, 0, stream>>>(emb, seg, gsum, gcnt);
    k_means<<<4, 256, 0, stream>>>(gsum, gcnt, means, mn);
    k_intra<<<256, 1024, 0, stream>>>(emb, seg, means, mn, acc);
    k_inter<<<NEDGE / 256, 256, 0, stream>>>(edges, means, mn, acc);
    k_final<<<1, 1, 0, stream>>>(acc, out);
}

// Round 3
// 528.264 us; speedup vs baseline: 1.0038x; 1.0038x over previous
//
#include <hip/hip_runtime.h>
#include <math.h>

#define N_PIX (1024 * 1024)
#define NSEG 1024
#define NCH 32
#define NEDGE 8192
#define EPS 1e-8f
#define INV_TAU 2.0f

// ws layout (floats):
//  gsum  [32][1024]  off 0        (layout [c][s])
//  gcnt  [1024]      off 32768
//  means [1024][32]  off 33792    (layout [s][c] for float4 gather)
//  mn    [1024]      off 66560    (clamped mean norms)
//  acc   [2]         off 67584    acc0 = sum_exp (intra+inter), acc1 = sum_intra
#define OFF_GSUM 0
#define OFF_GCNT 32768
#define OFF_MEANS 33792
#define OFF_MN 66560
#define OFF_ACC 67584
#define ZERO_FLOATS (OFF_ACC + 2)

// HW float atomics (ds_add_f32 / global_atomic_add_f32). Default atomicAdd on
// float lowers to a CAS retry loop (safe-FP semantics) -> ~260 cyc/op measured
// in round 1 (VALUBusy 0.5%). unsafeAtomicAdd emits the native instruction.
__device__ __forceinline__ void fadd(float* p, float v) { unsafeAtomicAdd(p, v); }

// ---------------------------------------------------------------------------
// Kernel 1: per-segment sums. 256 blocks = 32 channels x 8 pixel chunks.
// bid = j + 8*c  ->  XCD (bid%8) == chunk j, so all 32 channel-blocks of a
// chunk share one XCD's L2 for the seg reads. Each block privatizes a 4KB
// LDS histogram for its channel, then flushes 1024 coalesced global atomics.
// ---------------------------------------------------------------------------
__global__ __launch_bounds__(1024) void k_segsum(const float* __restrict__ emb,
                                                 const int* __restrict__ seg,
                                                 float* __restrict__ gsum,
                                                 float* __restrict__ gcnt) {
    __shared__ float lsum[NSEG];
    __shared__ float lcnt[NSEG];
    const int bid = blockIdx.x;
    const int c = bid >> 3;   // channel 0..31
    const int j = bid & 7;    // pixel chunk 0..7
    const int t = threadIdx.x;

    lsum[t] = 0.0f;
    if (c == 0) lcnt[t] = 0.0f;
    __syncthreads();

    const int chunk = N_PIX / 8;  // 131072 pixels
    const int base = j * chunk;
    const float* ec = emb + (size_t)c * N_PIX + base;
    const int* sg = seg + base;

    // 1024 threads * 32 iters * 4 pixels = 131072
#pragma unroll 4
    for (int it = 0; it < chunk / (1024 * 4); ++it) {
        const int idx = (it * 1024 + t) * 4;
        const float4 v = *(const float4*)(ec + idx);
        const int4 s4 = *(const int4*)(sg + idx);
        fadd(&lsum[s4.x], v.x);
        fadd(&lsum[s4.y], v.y);
        fadd(&lsum[s4.z], v.z);
        fadd(&lsum[s4.w], v.w);
        if (c == 0) {
            fadd(&lcnt[s4.x], 1.0f);
            fadd(&lcnt[s4.y], 1.0f);
            fadd(&lcnt[s4.z], 1.0f);
            fadd(&lcnt[s4.w], 1.0f);
        }
    }
    __syncthreads();

    fadd(&gsum[c * NSEG + t], lsum[t]);
    if (c == 0) fadd(&gcnt[t], lcnt[t]);
}

// ---------------------------------------------------------------------------
// Kernel 2: means (layout [s][c]) + clamped norms. One thread per segment.
// ---------------------------------------------------------------------------
__global__ void k_means(const float* __restrict__ gsum,
                        const float* __restrict__ gcnt,
                        float* __restrict__ means, float* __restrict__ mn) {
    const int s = blockIdx.x * blockDim.x + threadIdx.x;
    if (s >= NSEG) return;
    const float cnt = fmaxf(gcnt[s], 1.0f);
    const float inv = 1.0f / cnt;
    float nrm = 0.0f;
#pragma unroll
    for (int c = 0; c < NCH; ++c) {
        const float m = gsum[c * NSEG + s] * inv;
        means[s * NCH + c] = m;
        nrm += m * m;
    }
    mn[s] = fmaxf(sqrtf(nrm), EPS);
}

// ---------------------------------------------------------------------------
// Kernel 3: per-pixel intra = cos(mean[seg], emb) * 2; accumulate
// sum(exp(intra)) and sum(intra). 4 pixels/thread, float4 loads per channel.
// ---------------------------------------------------------------------------
__global__ __launch_bounds__(1024) void k_intra(const float* __restrict__ emb,
                                                const int* __restrict__ seg,
                                                const float* __restrict__ means,
                                                const float* __restrict__ mn,
                                                float* __restrict__ acc) {
    const int g = blockIdx.x * 1024 + threadIdx.x;
    const int n0 = g * 4;
    const int4 s4 = *(const int4*)(seg + n0);

    float dot0 = 0.f, dot1 = 0.f, dot2 = 0.f, dot3 = 0.f;
    float nr0 = 0.f, nr1 = 0.f, nr2 = 0.f, nr3 = 0.f;

#pragma unroll
    for (int c0 = 0; c0 < NCH; c0 += 4) {
        const float4 e0 = *(const float4*)(emb + (size_t)(c0 + 0) * N_PIX + n0);
        const float4 e1 = *(const float4*)(emb + (size_t)(c0 + 1) * N_PIX + n0);
        const float4 e2 = *(const float4*)(emb + (size_t)(c0 + 2) * N_PIX + n0);
        const float4 e3 = *(const float4*)(emb + (size_t)(c0 + 3) * N_PIX + n0);
        const float4 m0 = *(const float4*)(means + s4.x * NCH + c0);
        const float4 m1 = *(const float4*)(means + s4.y * NCH + c0);
        const float4 m2 = *(const float4*)(means + s4.z * NCH + c0);
        const float4 m3 = *(const float4*)(means + s4.w * NCH + c0);

        dot0 += m0.x * e0.x + m0.y * e1.x + m0.z * e2.x + m0.w * e3.x;
        dot1 += m1.x * e0.y + m1.y * e1.y + m1.z * e2.y + m1.w * e3.y;
        dot2 += m2.x * e0.z + m2.y * e1.z + m2.z * e2.z + m2.w * e3.z;
        dot3 += m3.x * e0.w + m3.y * e1.w + m3.z * e2.w + m3.w * e3.w;

        nr0 += e0.x * e0.x + e1.x * e1.x + e2.x * e2.x + e3.x * e3.x;
        nr1 += e0.y * e0.y + e1.y * e1.y + e2.y * e2.y + e3.y * e3.y;
        nr2 += e0.z * e0.z + e1.z * e1.z + e2.z * e2.z + e3.z * e3.z;
        nr3 += e0.w * e0.w + e1.w * e1.w + e2.w * e2.w + e3.w * e3.w;
    }

    float esum = 0.0f, isum = 0.0f;
    {
        const float i0 = dot0 / (fmaxf(sqrtf(nr0), EPS) * mn[s4.x]) * INV_TAU;
        const float i1 = dot1 / (fmaxf(sqrtf(nr1), EPS) * mn[s4.y]) * INV_TAU;
        const float i2 = dot2 / (fmaxf(sqrtf(nr2), EPS) * mn[s4.z]) * INV_TAU;
        const float i3 = dot3 / (fmaxf(sqrtf(nr3), EPS) * mn[s4.w]) * INV_TAU;
        esum = expf(i0) + expf(i1) + expf(i2) + expf(i3);
        isum = i0 + i1 + i2 + i3;
    }

    // wave (64-lane) reduce, then per-block reduce, then 2 atomics
#pragma unroll
    for (int off = 32; off > 0; off >>= 1) {
        esum += __shfl_down(esum, off);
        isum += __shfl_down(isum, off);
    }
    __shared__ float we[16], wi[16];
    const int wid = threadIdx.x >> 6;
    const int lane = threadIdx.x & 63;
    if (lane == 0) { we[wid] = esum; wi[wid] = isum; }
    __syncthreads();
    if (threadIdx.x == 0) {
        float a = 0.f, b = 0.f;
#pragma unroll
        for (int w = 0; w < 16; ++w) { a += we[w]; b += wi[w]; }
        fadd(&acc[0], a);
        fadd(&acc[1], b);
    }
}

// ---------------------------------------------------------------------------
// Kernel 4: inter edges — cos(mean[a], mean[b]) * 2, accumulate exp into acc0.
// ---------------------------------------------------------------------------
__global__ void k_inter(const int* __restrict__ edges,
                        const float* __restrict__ means,
                        const float* __restrict__ mn,
                        float* __restrict__ acc) {
    const int e = blockIdx.x * 256 + threadIdx.x;
    const int a = edges[e];
    const int b = edges[NEDGE + e];
    float dot = 0.0f;
#pragma unroll
    for (int c0 = 0; c0 < NCH; c0 += 4) {
        const float4 ma = *(const float4*)(means + a * NCH + c0);
        const float4 mb = *(const float4*)(means + b * NCH + c0);
        dot += ma.x * mb.x + ma.y * mb.y + ma.z * mb.z + ma.w * mb.w;
    }
    float ex = expf(dot / (mn[a] * mn[b]) * INV_TAU);
#pragma unroll
    for (int off = 32; off > 0; off >>= 1) ex += __shfl_down(ex, off);
    __shared__ float we[4];
    const int wid = threadIdx.x >> 6;
    const int lane = threadIdx.x & 63;
    if (lane == 0) we[wid] = ex;
    __syncthreads();
    if (threadIdx.x == 0) {
        fadd(&acc[0], we[0] + we[1] + we[2] + we[3]);
    }
}

// ---------------------------------------------------------------------------
// Kernel 5: out = log(sum_exp) - sum_intra / N
// ---------------------------------------------------------------------------
__global__ void k_final(const float* __restrict__ acc, float* __restrict__ out) {
    out[0] = logf(acc[0]) - acc[1] * (1.0f / (float)N_PIX);
}

extern "C" void kernel_launch(void* const* d_in, const int* in_sizes, int n_in,
                              void* d_out, int out_size, void* d_ws, size_t ws_size,
                              hipStream_t stream) {
    (void)in_sizes; (void)n_in; (void)out_size; (void)ws_size;
    const float* emb = (const float*)d_in[0];   // (32, 1024*1024) channel-major
    const int* seg = (const int*)d_in[1];       // (1024*1024,)
    const int* edges = (const int*)d_in[2];     // (2, 8192)
    float* out = (float*)d_out;

    float* ws = (float*)d_ws;
    float* gsum = ws + OFF_GSUM;
    float* gcnt = ws + OFF_GCNT;
    float* means = ws + OFF_MEANS;
    float* mn = ws + OFF_MN;
    float* acc = ws + OFF_ACC;

    // zero sums/counts/accumulators (ws is poisoned 0xAA before every launch)
    hipMemsetAsync(d_ws, 0, (size_t)ZERO_FLOATS * sizeof(float), stream);

    k_segsum<<<256, 1024, 0, stream>>>(emb, seg, gsum, gcnt);
    k_means<<<4, 256, 0, stream>>>(gsum, gcnt, means, mn);
    k_intra<<<256, 1024, 0, stream>>>(emb, seg, means, mn, acc);
    k_inter<<<NEDGE / 256, 256, 0, stream>>>(edges, means, mn, acc);
    k_final<<<1, 1, 0, stream>>>(acc, out);
}

// Round 4
// 253.159 us; speedup vs baseline: 2.0946x; 2.0867x over previous
//
#include <hip/hip_runtime.h>
#include <math.h>

#define N_PIX (1024 * 1024)
#define NSEG 1024
#define NCH 32
#define NCHUNK 8
#define NEDGE 8192
#define EPS 1e-8f
#define INV_TAU 2.0f
// Fixed-point scale for int32 LDS histogram accumulation.
// Per-(chunk,segment) partial |sum| <= ~1100 (max ~200 px/seg/chunk * |v|max ~5.5)
// -> representable bound 2^31/2^18 = 8192, ample. Quantization ~2^-19/add,
// ~1024 adds/segment -> ~1e-4 worst-case on segment sum; output threshold 0.28.
#define SCALE 262144.0f
#define INV_SCALE (1.0f / 262144.0f)

// ws layout (4-byte units). All regions fully WRITTEN before read each launch
// (plain stores, no accumulation) -> no memset needed, fully deterministic.
#define OFF_GSUMI 0                                   // int  [8][32][1024] chunk/channel partial sums
#define OFF_GCNTI (OFF_GSUMI + NCHUNK * NCH * NSEG)   // int  [8][32][1024] partial counts
#define OFF_MEANS (OFF_GCNTI + NCHUNK * NCH * NSEG)   // float[1024][32]
#define OFF_MN    (OFF_MEANS + NSEG * NCH)            // float[1024]
#define OFF_BPE   (OFF_MN + NSEG)                     // float[256]  per-block sum(exp(intra))
#define OFF_BPI   (OFF_BPE + 256)                     // float[256]  per-block sum(intra)
#define OFF_IPE   (OFF_BPI + 256)                     // float[32]   per-block sum(exp(inter))

// ---------------------------------------------------------------------------
// Kernel 1: per-segment sums, INT fixed-point LDS histogram (native ds_add_u32;
// float LDS atomics measured ~400 cyc/op serialized w/ ZERO bank conflicts ->
// non-native path, rounds 1-3). 256 blocks = 32 channels x 8 pixel chunks.
// bid = j + 8*c -> all 32 channel-blocks of chunk j land on XCD j (seg chunk
// L2-shared). Count duty: block c counts only iteration it==c (each pixel
// counted exactly once; perfectly balanced). Flush = plain coalesced stores
// into per-block-owned partial slabs -> zero global atomics.
// ---------------------------------------------------------------------------
__global__ __launch_bounds__(1024) void k_segsum(const float* __restrict__ emb,
                                                 const int* __restrict__ seg,
                                                 int* __restrict__ gsum_i,
                                                 int* __restrict__ gcnt_i) {
    __shared__ int lsum[NSEG];
    __shared__ int lcnt[NSEG];
    const int bid = blockIdx.x;
    const int c = bid >> 3;   // channel 0..31
    const int j = bid & 7;    // pixel chunk 0..7
    const int t = threadIdx.x;

    lsum[t] = 0;
    lcnt[t] = 0;
    __syncthreads();

    const int chunk = N_PIX / NCHUNK;  // 131072 pixels
    const float* ec = emb + (size_t)c * N_PIX + (size_t)j * chunk;
    const int* sg = seg + j * chunk;

    // 32 iterations: 1024 threads * 4 pixels each
    for (int it = 0; it < chunk / (1024 * 4); ++it) {
        const int idx = (it * 1024 + t) * 4;
        const float4 v = *(const float4*)(ec + idx);
        const int4 s4 = *(const int4*)(sg + idx);
        atomicAdd(&lsum[s4.x], __float2int_rn(v.x * SCALE));
        atomicAdd(&lsum[s4.y], __float2int_rn(v.y * SCALE));
        atomicAdd(&lsum[s4.z], __float2int_rn(v.z * SCALE));
        atomicAdd(&lsum[s4.w], __float2int_rn(v.w * SCALE));
        if (it == c) {  // this block's counting slice
            atomicAdd(&lcnt[s4.x], 1);
            atomicAdd(&lcnt[s4.y], 1);
            atomicAdd(&lcnt[s4.z], 1);
            atomicAdd(&lcnt[s4.w], 1);
        }
    }
    __syncthreads();

    gsum_i[(j * NCH + c) * NSEG + t] = lsum[t];  // plain stores, block-owned slab
    gcnt_i[(j * NCH + c) * NSEG + t] = lcnt[t];
}

// ---------------------------------------------------------------------------
// Kernel 2: combine int partials (exact int adds) -> means [s][c] + clamped
// norms. 4 blocks x 256 threads; s = global thread -> all loads coalesced.
// ---------------------------------------------------------------------------
__global__ void k_means(const int* __restrict__ gsum_i,
                        const int* __restrict__ gcnt_i,
                        float* __restrict__ means, float* __restrict__ mn) {
    const int s = blockIdx.x * 256 + threadIdx.x;
    int cnt_i = 0;
#pragma unroll 8
    for (int p = 0; p < NCHUNK * NCH; ++p) cnt_i += gcnt_i[p * NSEG + s];
    const float inv = 1.0f / fmaxf((float)cnt_i, 1.0f);
    float nrm = 0.0f;
#pragma unroll
    for (int c = 0; c < NCH; ++c) {
        int a = 0;
#pragma unroll
        for (int j = 0; j < NCHUNK; ++j) a += gsum_i[(j * NCH + c) * NSEG + s];
        const float m = (float)a * INV_SCALE * inv;
        means[s * NCH + c] = m;
        nrm += m * m;
    }
    mn[s] = fmaxf(sqrtf(nrm), EPS);
}

// ---------------------------------------------------------------------------
// Kernel 3: per-pixel intra = cos(mean[seg], emb) * 2; per-block partial
// sums of exp(intra) and intra written as plain stores (no atomics).
// ---------------------------------------------------------------------------
__global__ __launch_bounds__(1024) void k_intra(const float* __restrict__ emb,
                                                const int* __restrict__ seg,
                                                const float* __restrict__ means,
                                                const float* __restrict__ mn,
                                                float* __restrict__ bpe,
                                                float* __restrict__ bpi) {
    const int g = blockIdx.x * 1024 + threadIdx.x;
    const int n0 = g * 4;
    const int4 s4 = *(const int4*)(seg + n0);

    float dot0 = 0.f, dot1 = 0.f, dot2 = 0.f, dot3 = 0.f;
    float nr0 = 0.f, nr1 = 0.f, nr2 = 0.f, nr3 = 0.f;

#pragma unroll
    for (int c0 = 0; c0 < NCH; c0 += 4) {
        const float4 e0 = *(const float4*)(emb + (size_t)(c0 + 0) * N_PIX + n0);
        const float4 e1 = *(const float4*)(emb + (size_t)(c0 + 1) * N_PIX + n0);
        const float4 e2 = *(const float4*)(emb + (size_t)(c0 + 2) * N_PIX + n0);
        const float4 e3 = *(const float4*)(emb + (size_t)(c0 + 3) * N_PIX + n0);
        const float4 m0 = *(const float4*)(means + s4.x * NCH + c0);
        const float4 m1 = *(const float4*)(means + s4.y * NCH + c0);
        const float4 m2 = *(const float4*)(means + s4.z * NCH + c0);
        const float4 m3 = *(const float4*)(means + s4.w * NCH + c0);

        dot0 += m0.x * e0.x + m0.y * e1.x + m0.z * e2.x + m0.w * e3.x;
        dot1 += m1.x * e0.y + m1.y * e1.y + m1.z * e2.y + m1.w * e3.y;
        dot2 += m2.x * e0.z + m2.y * e1.z + m2.z * e2.z + m2.w * e3.z;
        dot3 += m3.x * e0.w + m3.y * e1.w + m3.z * e2.w + m3.w * e3.w;

        nr0 += e0.x * e0.x + e1.x * e1.x + e2.x * e2.x + e3.x * e3.x;
        nr1 += e0.y * e0.y + e1.y * e1.y + e2.y * e2.y + e3.y * e3.y;
        nr2 += e0.z * e0.z + e1.z * e1.z + e2.z * e2.z + e3.z * e3.z;
        nr3 += e0.w * e0.w + e1.w * e1.w + e2.w * e2.w + e3.w * e3.w;
    }

    const float i0 = dot0 / (fmaxf(sqrtf(nr0), EPS) * mn[s4.x]) * INV_TAU;
    const float i1 = dot1 / (fmaxf(sqrtf(nr1), EPS) * mn[s4.y]) * INV_TAU;
    const float i2 = dot2 / (fmaxf(sqrtf(nr2), EPS) * mn[s4.z]) * INV_TAU;
    const float i3 = dot3 / (fmaxf(sqrtf(nr3), EPS) * mn[s4.w]) * INV_TAU;
    float esum = expf(i0) + expf(i1) + expf(i2) + expf(i3);
    float isum = i0 + i1 + i2 + i3;

#pragma unroll
    for (int off = 32; off > 0; off >>= 1) {
        esum += __shfl_down(esum, off);
        isum += __shfl_down(isum, off);
    }
    __shared__ float we[16], wi[16];
    const int wid = threadIdx.x >> 6;
    const int lane = threadIdx.x & 63;
    if (lane == 0) { we[wid] = esum; wi[wid] = isum; }
    __syncthreads();
    if (threadIdx.x == 0) {
        float a = 0.f, b = 0.f;
#pragma unroll
        for (int w = 0; w < 16; ++w) { a += we[w]; b += wi[w]; }
        bpe[blockIdx.x] = a;
        bpi[blockIdx.x] = b;
    }
}

// ---------------------------------------------------------------------------
// Kernel 4: inter edges — cos(mean[a], mean[b]) * 2; per-block partial store.
// ---------------------------------------------------------------------------
__global__ void k_inter(const int* __restrict__ edges,
                        const float* __restrict__ means,
                        const float* __restrict__ mn,
                        float* __restrict__ ipe) {
    const int e = blockIdx.x * 256 + threadIdx.x;
    const int a = edges[e];
    const int b = edges[NEDGE + e];
    float dot = 0.0f;
#pragma unroll
    for (int c0 = 0; c0 < NCH; c0 += 4) {
        const float4 ma = *(const float4*)(means + a * NCH + c0);
        const float4 mb = *(const float4*)(means + b * NCH + c0);
        dot += ma.x * mb.x + ma.y * mb.y + ma.z * mb.z + ma.w * mb.w;
    }
    float ex = expf(dot / (mn[a] * mn[b]) * INV_TAU);
#pragma unroll
    for (int off = 32; off > 0; off >>= 1) ex += __shfl_down(ex, off);
    __shared__ float we[4];
    const int wid = threadIdx.x >> 6;
    const int lane = threadIdx.x & 63;
    if (lane == 0) we[wid] = ex;
    __syncthreads();
    if (threadIdx.x == 0) ipe[blockIdx.x] = we[0] + we[1] + we[2] + we[3];
}

// ---------------------------------------------------------------------------
// Kernel 5: reduce 256 intra partials + 32 inter partials ->
// out = log(sum_exp) - sum_intra / N. One 256-thread block, deterministic.
// ---------------------------------------------------------------------------
__global__ void k_final(const float* __restrict__ bpe,
                        const float* __restrict__ bpi,
                        const float* __restrict__ ipe,
                        float* __restrict__ out) {
    const int t = threadIdx.x;  // 256
    float e = bpe[t] + (t < 32 ? ipe[t] : 0.0f);
    float i = bpi[t];
#pragma unroll
    for (int off = 32; off > 0; off >>= 1) {
        e += __shfl_down(e, off);
        i += __shfl_down(i, off);
    }
    __shared__ float we[4], wi[4];
    const int wid = t >> 6;
    const int lane = t & 63;
    if (lane == 0) { we[wid] = e; wi[wid] = i; }
    __syncthreads();
    if (t == 0) {
        const float E = we[0] + we[1] + we[2] + we[3];
        const float I = wi[0] + wi[1] + wi[2] + wi[3];
        out[0] = logf(E) - I * (1.0f / (float)N_PIX);
    }
}

extern "C" void kernel_launch(void* const* d_in, const int* in_sizes, int n_in,
                              void* d_out, int out_size, void* d_ws, size_t ws_size,
                              hipStream_t stream) {
    (void)in_sizes; (void)n_in; (void)out_size; (void)ws_size;
    const float* emb = (const float*)d_in[0];   // (32, 1024*1024) channel-major
    const int* seg = (const int*)d_in[1];       // (1024*1024,)
    const int* edges = (const int*)d_in[2];     // (2, 8192)
    float* out = (float*)d_out;

    int* wsi = (int*)d_ws;
    float* wsf = (float*)d_ws;
    int* gsum_i = wsi + OFF_GSUMI;
    int* gcnt_i = wsi + OFF_GCNTI;
    float* means = wsf + OFF_MEANS;
    float* mn = wsf + OFF_MN;
    float* bpe = wsf + OFF_BPE;
    float* bpi = wsf + OFF_BPI;
    float* ipe = wsf + OFF_IPE;

    k_segsum<<<256, 1024, 0, stream>>>(emb, seg, gsum_i, gcnt_i);
    k_means<<<4, 256, 0, stream>>>(gsum_i, gcnt_i, means, mn);
    k_intra<<<256, 1024, 0, stream>>>(emb, seg, means, mn, bpe, bpi);
    k_inter<<<NEDGE / (256 * 1), 256, 0, stream>>>(edges, means, mn, ipe);
    k_final<<<1, 256, 0, stream>>>(bpe, bpi, ipe, out);
}